// Round 3
// baseline (587.889 us; speedup 1.0000x reference)
//
#include <hip/hip_runtime.h>
#include <stdint.h>

#define F_IN  128
#define HID   16
#define F_OUT 128
#define NB    1024   // coarse dst buckets

// ---------- utility ----------
__global__ void k_zero(int* __restrict__ p, int n) {
    int i = blockIdx.x * blockDim.x + threadIdx.x;
    if (i < n) p[i] = 0;
}

__device__ __forceinline__ int bucket_of(int d, int N) {
    return (int)(((long long)d * NB) / N);
}

// ---------- pass A: coarse histogram over dst buckets (LDS-staged) ----------
__global__ void k_bhist(const int* __restrict__ dst, int* __restrict__ bh, int E, int N) {
    __shared__ int h[NB];
    int t = threadIdx.x;
    for (int i = t; i < NB; i += 256) h[i] = 0;
    __syncthreads();
    for (int e = blockIdx.x * 256 + t; e < E; e += gridDim.x * 256)
        atomicAdd(&h[bucket_of(dst[e], N)], 1);
    __syncthreads();
    for (int i = t; i < NB; i += 256) {
        int v = h[i];
        if (v) atomicAdd(&bh[i], v);
    }
}

// ---------- pass B: scan bucket counts (single block, NB threads) ----------
__global__ void k_bscan(const int* __restrict__ bh, int* __restrict__ bstart,
                        int* __restrict__ bcur) {
    __shared__ int s[NB];
    int t = threadIdx.x;
    int v = bh[t];
    s[t] = v; __syncthreads();
    for (int o = 1; o < NB; o <<= 1) {
        int x = (t >= o) ? s[t - o] : 0;
        __syncthreads();
        s[t] += x;
        __syncthreads();
    }
    int excl = s[t] - v;
    bstart[t] = excl;
    bcur[t]   = excl;
    if (t == NB - 1) bstart[NB] = s[t];
}

// ---------- pass C: partition (src,dst) pairs into bucket order ----------
__global__ void k_part(const int* __restrict__ ei, int* __restrict__ bcur,
                       int2* __restrict__ pairs, int E, int N) {
    int e = blockIdx.x * blockDim.x + threadIdx.x;
    if (e >= E) return;
    int s = ei[e];
    int d = ei[E + e];
    int b = bucket_of(d, N);
    int pos = atomicAdd(&bcur[b], 1);
    pairs[pos] = make_int2(s, d);
}

// ---------- pass D: per-bucket CSR build (block = bucket, all LDS-local) ----------
__global__ void k_csr(const int2* __restrict__ pairs, const int* __restrict__ bstart,
                      int* __restrict__ row_start, int* __restrict__ cnt,
                      float* __restrict__ dinv, int* __restrict__ srcs, int N) {
    __shared__ int lcnt[128];
    __shared__ int loff[128];
    __shared__ int lcur[128];
    int b = blockIdx.x, t = threadIdx.x;
    int e0 = bstart[b], e1 = bstart[b + 1];
    int nlo = (int)(((long long)b * N + NB - 1) / NB);
    int nhi = (int)(((long long)(b + 1) * N + NB - 1) / NB);
    if (nhi > N) nhi = N;
    int nn = nhi - nlo;          // <= 98 for N=100000
    if (t < 128) lcnt[t] = 0;
    __syncthreads();
    for (int e = e0 + t; e < e1; e += 256)
        atomicAdd(&lcnt[pairs[e].y - nlo], 1);
    __syncthreads();
    int v = (t < 128) ? lcnt[t] : 0;
    if (t < 128) loff[t] = v;
    __syncthreads();
    for (int o = 1; o < 128; o <<= 1) {
        int x = (t < 128 && t >= o) ? loff[t - o] : 0;
        __syncthreads();
        if (t < 128) loff[t] += x;
        __syncthreads();
    }
    if (t < nn) {
        int gs = e0 + (loff[t] - v);   // exclusive scan
        row_start[nlo + t] = gs;
        cnt[nlo + t]       = v;
        dinv[nlo + t]      = rsqrtf((float)(v + 1));
        lcur[t]            = gs;
    }
    __syncthreads();
    for (int e = e0 + t; e < e1; e += 256) {
        int2 p = pairs[e];
        int pos = atomicAdd(&lcur[p.y - nlo], 1);
        srcs[pos] = p.x;
    }
}

// ---------- layer 1 transform: g1 = dinv * (x @ W1) ----------
__global__ void k_transform1(const float* __restrict__ x, const float* __restrict__ W1,
                             const float* __restrict__ dinv,
                             float* __restrict__ g1, int n) {
    __shared__ float sW[F_IN * HID];   // [k][f]
    __shared__ float sX[16 * F_IN];
    int t = threadIdx.x;
    for (int i = t; i < F_IN * HID; i += 256) sW[i] = W1[i];
    int node0 = blockIdx.x * 16;
    const float* xb = x + (size_t)node0 * F_IN;
    for (int i = t; i < 16 * F_IN; i += 256) {
        int node = node0 + (i >> 7);
        sX[i] = (node < n) ? xb[i] : 0.0f;
    }
    __syncthreads();
    int nl = t >> 4, f = t & 15;
    int node = node0 + nl;
    if (node >= n) return;
    float s = 0.0f;
#pragma unroll
    for (int k = 0; k < F_IN; ++k)
        s += sX[nl * F_IN + k] * sW[k * HID + f];
    g1[(size_t)node * HID + f] = dinv[node] * s;
}

// ---------- gather-aggregate: out[i] = g[i] + sum_j g[srcs[rs+j]] ----------
template<bool EP1>
__global__ void k_gather(const float* __restrict__ g, const int* __restrict__ srcs,
                         const int* __restrict__ row_start, const int* __restrict__ cnt,
                         const float* __restrict__ dinv, const float* __restrict__ b1,
                         float* __restrict__ outb, int n) {
    int t = blockIdx.x * blockDim.x + threadIdx.x;
    int node = t >> 2;
    int p = t & 3;
    if (node >= n) return;
    int rs  = row_start[node];
    int deg = cnt[node];
    float4 acc = *(const float4*)(g + (size_t)node * HID + p * 4);
    int j = 0;
    for (; j + 4 <= deg; j += 4) {
        int s0 = srcs[rs + j + 0];
        int s1 = srcs[rs + j + 1];
        int s2 = srcs[rs + j + 2];
        int s3 = srcs[rs + j + 3];
        float4 v0 = *(const float4*)(g + (size_t)s0 * HID + p * 4);
        float4 v1 = *(const float4*)(g + (size_t)s1 * HID + p * 4);
        float4 v2 = *(const float4*)(g + (size_t)s2 * HID + p * 4);
        float4 v3 = *(const float4*)(g + (size_t)s3 * HID + p * 4);
        acc.x += (v0.x + v1.x) + (v2.x + v3.x);
        acc.y += (v0.y + v1.y) + (v2.y + v3.y);
        acc.z += (v0.z + v1.z) + (v2.z + v3.z);
        acc.w += (v0.w + v1.w) + (v2.w + v3.w);
    }
    for (; j < deg; ++j) {
        int s0 = srcs[rs + j];
        float4 v0 = *(const float4*)(g + (size_t)s0 * HID + p * 4);
        acc.x += v0.x; acc.y += v0.y; acc.z += v0.z; acc.w += v0.w;
    }
    if (EP1) {
        float di = dinv[node];
        acc.x = di * fmaxf(di * acc.x + b1[p * 4 + 0], 0.0f);
        acc.y = di * fmaxf(di * acc.y + b1[p * 4 + 1], 0.0f);
        acc.z = di * fmaxf(di * acc.z + b1[p * 4 + 2], 0.0f);
        acc.w = di * fmaxf(di * acc.w + b1[p * 4 + 3], 0.0f);
    }
    *(float4*)(outb + (size_t)node * HID + p * 4) = acc;
}

// ---------- layer 2 transform: out = relu((dinv*agg) @ W2 + b2) ----------
__global__ void k_transform2(const float* __restrict__ agg, const float* __restrict__ W2,
                             const float* __restrict__ b2, const float* __restrict__ dinv,
                             float* __restrict__ out, int n) {
    __shared__ float sW[HID * F_OUT];  // [f][d]
    __shared__ float sB[F_OUT];
    __shared__ float sV[2 * HID];
    int t = threadIdx.x;
    for (int i = t; i < HID * F_OUT; i += 256) sW[i] = W2[i];
    if (t < F_OUT) sB[t] = b2[t];
    int node0 = blockIdx.x * 2;
    if (t < 2 * HID) {
        int node = node0 + (t >> 4);
        sV[t] = (node < n) ? dinv[node] * agg[(size_t)node * HID + (t & 15)] : 0.0f;
    }
    __syncthreads();
    int nl = t >> 7, d = t & 127;
    int node = node0 + nl;
    if (node >= n) return;
    float s = 0.0f;
#pragma unroll
    for (int f = 0; f < HID; ++f)
        s += sV[nl * HID + f] * sW[f * F_OUT + d];
    out[(size_t)node * F_OUT + d] = fmaxf(s + sB[d], 0.0f);
}

extern "C" void kernel_launch(void* const* d_in, const int* in_sizes, int n_in,
                              void* d_out, int out_size, void* d_ws, size_t ws_size,
                              hipStream_t stream) {
    const float* x  = (const float*)d_in[0];
    const int*   ei = (const int*)d_in[1];
    const float* W1 = (const float*)d_in[2];
    const float* b1 = (const float*)d_in[3];
    const float* W2 = (const float*)d_in[4];
    const float* b2 = (const float*)d_in[5];
    float* out = (float*)d_out;

    const int N = in_sizes[0] / F_IN;
    const int E = in_sizes[1] / 2;

    // workspace layout
    float* dinv      = (float*)d_ws;                   // N
    int*   cnt       = (int*)(dinv + N);               // N
    int*   row_start = cnt + N;                        // N
    int*   bh        = row_start + N;                  // NB
    int*   bstart    = bh + NB;                        // NB+1
    int*   bcur      = bstart + NB + 1;                // NB
    int*   srcs      = bcur + NB;                      // E
    uintptr_t xb = (uintptr_t)(srcs + E);
    xb = (xb + 15) & ~(uintptr_t)15;                   // 16B align
    int2*  pairs = (int2*)xb;                          // E int2 (build phase)
    float* bufA  = (float*)xb;                         // N*HID (overlaps pairs; used after)
    float* bufB  = bufA + (size_t)N * HID;             // N*HID

    k_zero <<<(NB + 255) / 256, 256, 0, stream>>>(bh, NB);
    k_bhist<<<256, 256, 0, stream>>>(ei + E, bh, E, N);
    k_bscan<<<1, NB, 0, stream>>>(bh, bstart, bcur);
    k_part <<<(E + 255) / 256, 256, 0, stream>>>(ei, bcur, pairs, E, N);
    k_csr  <<<NB, 256, 0, stream>>>(pairs, bstart, row_start, cnt, dinv, srcs, N);

    k_transform1<<<(N + 15) / 16, 256, 0, stream>>>(x, W1, dinv, bufA, N);
    k_gather<true> <<<((size_t)N * 4 + 255) / 256, 256, 0, stream>>>(
        bufA, srcs, row_start, cnt, dinv, b1, bufB, N);
    k_gather<false><<<((size_t)N * 4 + 255) / 256, 256, 0, stream>>>(
        bufB, srcs, row_start, cnt, dinv, b1, bufA, N);
    k_transform2<<<(N + 1) / 2, 256, 0, stream>>>(bufA, W2, b2, dinv, out, N);
}

// Round 4
// 303.810 us; speedup vs baseline: 1.9351x; 1.9351x over previous
//
#include <hip/hip_runtime.h>
#include <stdint.h>

#define F_IN  128
#define HID   16
#define F_OUT 128
#define NBK   256    // coarse dst buckets
#define NBLK  256    // partition blocks
#define LCAP  512    // per-bucket node capacity (>= ceil(N/NBK)+1)

__global__ void k_zero(int* __restrict__ p, int n) {
    int i = blockIdx.x * blockDim.x + threadIdx.x;
    if (i < n) p[i] = 0;
}

__device__ __forceinline__ int bucket_of(int d, int N) {
    return (int)(((long long)d * NBK) / N);
}

// ---------- pass A: coarse histogram over dst buckets (LDS-staged) ----------
__global__ void k_bhist(const int* __restrict__ dst, int* __restrict__ bh, int E, int N) {
    __shared__ int h[NBK];
    int t = threadIdx.x;
    for (int i = t; i < NBK; i += 256) h[i] = 0;
    __syncthreads();
    for (int e = blockIdx.x * 256 + t; e < E; e += gridDim.x * 256)
        atomicAdd(&h[bucket_of(dst[e], N)], 1);
    __syncthreads();
    int i = (t + blockIdx.x) & (NBK - 1);   // rotate to stagger contention
    int v = h[i];
    if (v) atomicAdd(&bh[i], v);
}

// ---------- pass B: scan bucket counts (single block, 256 threads) ----------
__global__ void k_bscan(const int* __restrict__ bh, int* __restrict__ bstart,
                        int* __restrict__ bcur) {
    __shared__ int s[NBK];
    int t = threadIdx.x;
    int v = bh[t];
    s[t] = v; __syncthreads();
    for (int o = 1; o < NBK; o <<= 1) {
        int x = (t >= o) ? s[t - o] : 0;
        __syncthreads();
        s[t] += x;
        __syncthreads();
    }
    int excl = s[t] - v;
    bstart[t] = excl;
    bcur[t]   = excl;
    if (t == NBK - 1) bstart[NBK] = s[t];
}

// ---------- pass C: partition with per-block range reservation ----------
__global__ void k_part2(const int* __restrict__ ei, int* __restrict__ bcur,
                        int2* __restrict__ pairs, int E, int N) {
    __shared__ int lh[NBK], lbase[NBK], lcur[NBK];
    int blk = blockIdx.x, t = threadIdx.x;
    int C = (E + NBLK - 1) / NBLK;
    int e0 = blk * C;
    int e1 = e0 + C; if (e1 > E) e1 = E;
    for (int i = t; i < NBK; i += 256) { lh[i] = 0; lcur[i] = 0; }
    __syncthreads();
    for (int e = e0 + t; e < e1; e += 256)
        atomicAdd(&lh[bucket_of(ei[E + e], N)], 1);
    __syncthreads();
    {   // one global atomic per (block,bucket), rotated to stagger
        int i = (t + blk) & (NBK - 1);
        lbase[i] = lh[i] ? atomicAdd(&bcur[i], lh[i]) : 0;
    }
    __syncthreads();
    for (int e = e0 + t; e < e1; e += 256) {
        int s = ei[e];
        int d = ei[E + e];
        int b = bucket_of(d, N);
        int pos = lbase[b] + atomicAdd(&lcur[b], 1);
        pairs[pos] = make_int2(s, d);
    }
}

// ---------- pass D: per-bucket CSR build (block = bucket, LDS-local) ----------
__global__ void k_csr(const int2* __restrict__ pairs, const int* __restrict__ bstart,
                      int* __restrict__ row_start, int* __restrict__ cnt,
                      float* __restrict__ dinv, int* __restrict__ srcs, int N) {
    __shared__ int lcnt[LCAP];
    __shared__ int loff[LCAP];
    __shared__ int lcur[LCAP];
    int b = blockIdx.x, t = threadIdx.x;
    int e0 = bstart[b], e1 = bstart[b + 1];
    int nlo = (int)(((long long)b * N + NBK - 1) / NBK);
    int nhi = (int)(((long long)(b + 1) * N + NBK - 1) / NBK);
    if (nhi > N) nhi = N;
    int nn = nhi - nlo;                     // <= 391
    lcnt[t] = 0; lcnt[t + 256] = 0;
    __syncthreads();
    for (int e = e0 + t; e < e1; e += 256)
        atomicAdd(&lcnt[pairs[e].y - nlo], 1);
    __syncthreads();
    int v0 = lcnt[t], v1 = lcnt[t + 256];
    loff[t] = v0; loff[t + 256] = v1;
    __syncthreads();
    for (int o = 1; o < LCAP; o <<= 1) {
        int a0 = (t >= o) ? loff[t - o] : 0;
        int a1 = (t + 256 >= o) ? loff[t + 256 - o] : 0;
        __syncthreads();
        loff[t] += a0; loff[t + 256] += a1;
        __syncthreads();
    }
    if (t < nn) {
        int gs = e0 + (loff[t] - v0);       // exclusive
        row_start[nlo + t] = gs;
        cnt[nlo + t]       = v0;
        dinv[nlo + t]      = rsqrtf((float)(v0 + 1));
        lcur[t]            = gs;
    }
    int t2 = t + 256;
    if (t2 < nn) {
        int gs = e0 + (loff[t2] - v1);
        row_start[nlo + t2] = gs;
        cnt[nlo + t2]       = v1;
        dinv[nlo + t2]      = rsqrtf((float)(v1 + 1));
        lcur[t2]            = gs;
    }
    __syncthreads();
    for (int e = e0 + t; e < e1; e += 256) {
        int2 p = pairs[e];
        int pos = atomicAdd(&lcur[p.y - nlo], 1);
        srcs[pos] = p.x;
    }
}

// ---------- layer 1 transform: g1 = dinv * (x @ W1) ----------
__global__ void k_transform1(const float* __restrict__ x, const float* __restrict__ W1,
                             const float* __restrict__ dinv,
                             float* __restrict__ g1, int n) {
    __shared__ float sW[F_IN * HID];   // [k][f]
    __shared__ float sX[16 * F_IN];
    int t = threadIdx.x;
    for (int i = t; i < F_IN * HID; i += 256) sW[i] = W1[i];
    int node0 = blockIdx.x * 16;
    const float* xb = x + (size_t)node0 * F_IN;
    for (int i = t; i < 16 * F_IN; i += 256) {
        int node = node0 + (i >> 7);
        sX[i] = (node < n) ? xb[i] : 0.0f;
    }
    __syncthreads();
    int nl = t >> 4, f = t & 15;
    int node = node0 + nl;
    if (node >= n) return;
    float s = 0.0f;
#pragma unroll
    for (int k = 0; k < F_IN; ++k)
        s += sX[nl * F_IN + k] * sW[k * HID + f];
    g1[(size_t)node * HID + f] = dinv[node] * s;
}

// ---------- gather-aggregate: out[i] = g[i] + sum_j g[srcs[rs+j]] ----------
template<bool EP1>
__global__ void k_gather(const float* __restrict__ g, const int* __restrict__ srcs,
                         const int* __restrict__ row_start, const int* __restrict__ cnt,
                         const float* __restrict__ dinv, const float* __restrict__ b1,
                         float* __restrict__ outb, int n) {
    int t = blockIdx.x * blockDim.x + threadIdx.x;
    int node = t >> 2;
    int p = t & 3;
    if (node >= n) return;
    int rs  = row_start[node];
    int deg = cnt[node];
    float4 acc = *(const float4*)(g + (size_t)node * HID + p * 4);
    int j = 0;
    for (; j + 8 <= deg; j += 8) {
        int s0 = srcs[rs + j + 0], s1 = srcs[rs + j + 1];
        int s2 = srcs[rs + j + 2], s3 = srcs[rs + j + 3];
        int s4 = srcs[rs + j + 4], s5 = srcs[rs + j + 5];
        int s6 = srcs[rs + j + 6], s7 = srcs[rs + j + 7];
        float4 v0 = *(const float4*)(g + (size_t)s0 * HID + p * 4);
        float4 v1 = *(const float4*)(g + (size_t)s1 * HID + p * 4);
        float4 v2 = *(const float4*)(g + (size_t)s2 * HID + p * 4);
        float4 v3 = *(const float4*)(g + (size_t)s3 * HID + p * 4);
        float4 v4 = *(const float4*)(g + (size_t)s4 * HID + p * 4);
        float4 v5 = *(const float4*)(g + (size_t)s5 * HID + p * 4);
        float4 v6 = *(const float4*)(g + (size_t)s6 * HID + p * 4);
        float4 v7 = *(const float4*)(g + (size_t)s7 * HID + p * 4);
        acc.x += ((v0.x + v1.x) + (v2.x + v3.x)) + ((v4.x + v5.x) + (v6.x + v7.x));
        acc.y += ((v0.y + v1.y) + (v2.y + v3.y)) + ((v4.y + v5.y) + (v6.y + v7.y));
        acc.z += ((v0.z + v1.z) + (v2.z + v3.z)) + ((v4.z + v5.z) + (v6.z + v7.z));
        acc.w += ((v0.w + v1.w) + (v2.w + v3.w)) + ((v4.w + v5.w) + (v6.w + v7.w));
    }
    for (; j + 2 <= deg; j += 2) {
        int s0 = srcs[rs + j], s1 = srcs[rs + j + 1];
        float4 v0 = *(const float4*)(g + (size_t)s0 * HID + p * 4);
        float4 v1 = *(const float4*)(g + (size_t)s1 * HID + p * 4);
        acc.x += v0.x + v1.x; acc.y += v0.y + v1.y;
        acc.z += v0.z + v1.z; acc.w += v0.w + v1.w;
    }
    if (j < deg) {
        int s0 = srcs[rs + j];
        float4 v0 = *(const float4*)(g + (size_t)s0 * HID + p * 4);
        acc.x += v0.x; acc.y += v0.y; acc.z += v0.z; acc.w += v0.w;
    }
    if (EP1) {
        float di = dinv[node];
        acc.x = di * fmaxf(di * acc.x + b1[p * 4 + 0], 0.0f);
        acc.y = di * fmaxf(di * acc.y + b1[p * 4 + 1], 0.0f);
        acc.z = di * fmaxf(di * acc.z + b1[p * 4 + 2], 0.0f);
        acc.w = di * fmaxf(di * acc.w + b1[p * 4 + 3], 0.0f);
    }
    *(float4*)(outb + (size_t)node * HID + p * 4) = acc;
}

// ---------- layer 2 transform: out = relu((dinv*agg) @ W2 + b2) ----------
__global__ void k_transform2(const float* __restrict__ agg, const float* __restrict__ W2,
                             const float* __restrict__ b2, const float* __restrict__ dinv,
                             float* __restrict__ out, int n) {
    __shared__ float sW[HID * F_OUT];  // [f][d]
    __shared__ float sB[F_OUT];
    __shared__ float sV[2 * HID];
    int t = threadIdx.x;
    for (int i = t; i < HID * F_OUT; i += 256) sW[i] = W2[i];
    if (t < F_OUT) sB[t] = b2[t];
    int node0 = blockIdx.x * 2;
    if (t < 2 * HID) {
        int node = node0 + (t >> 4);
        sV[t] = (node < n) ? dinv[node] * agg[(size_t)node * HID + (t & 15)] : 0.0f;
    }
    __syncthreads();
    int nl = t >> 7, d = t & 127;
    int node = node0 + nl;
    if (node >= n) return;
    float s = 0.0f;
#pragma unroll
    for (int f = 0; f < HID; ++f)
        s += sV[nl * HID + f] * sW[f * F_OUT + d];
    out[(size_t)node * F_OUT + d] = fmaxf(s + sB[d], 0.0f);
}

extern "C" void kernel_launch(void* const* d_in, const int* in_sizes, int n_in,
                              void* d_out, int out_size, void* d_ws, size_t ws_size,
                              hipStream_t stream) {
    const float* x  = (const float*)d_in[0];
    const int*   ei = (const int*)d_in[1];
    const float* W1 = (const float*)d_in[2];
    const float* b1 = (const float*)d_in[3];
    const float* W2 = (const float*)d_in[4];
    const float* b2 = (const float*)d_in[5];
    float* out = (float*)d_out;

    const int N = in_sizes[0] / F_IN;
    const int E = in_sizes[1] / 2;

    // workspace layout
    float* dinv      = (float*)d_ws;                   // N
    int*   cnt       = (int*)(dinv + N);               // N
    int*   row_start = cnt + N;                        // N
    int*   bh        = row_start + N;                  // NBK
    int*   bstart    = bh + NBK;                       // NBK+1
    int*   bcur      = bstart + NBK + 1;               // NBK
    int*   srcs      = bcur + NBK;                     // E
    uintptr_t xb = (uintptr_t)(srcs + E);
    xb = (xb + 15) & ~(uintptr_t)15;
    int2*  pairs = (int2*)xb;                          // E int2 (build phase)
    float* bufA  = (float*)xb;                         // N*HID (reuses pairs region)
    float* bufB  = bufA + (size_t)N * HID;             // N*HID

    k_zero <<<1, NBK, 0, stream>>>(bh, NBK);
    k_bhist<<<256, 256, 0, stream>>>(ei + E, bh, E, N);
    k_bscan<<<1, NBK, 0, stream>>>(bh, bstart, bcur);
    k_part2<<<NBLK, 256, 0, stream>>>(ei, bcur, pairs, E, N);
    k_csr  <<<NBK, 256, 0, stream>>>(pairs, bstart, row_start, cnt, dinv, srcs, N);

    k_transform1<<<(N + 15) / 16, 256, 0, stream>>>(x, W1, dinv, bufA, N);
    k_gather<true> <<<((size_t)N * 4 + 255) / 256, 256, 0, stream>>>(
        bufA, srcs, row_start, cnt, dinv, b1, bufB, N);
    k_gather<false><<<((size_t)N * 4 + 255) / 256, 256, 0, stream>>>(
        bufB, srcs, row_start, cnt, dinv, b1, bufA, N);
    k_transform2<<<(N + 1) / 2, 256, 0, stream>>>(bufA, W2, b2, dinv, out, N);
}

// Round 5
// 298.522 us; speedup vs baseline: 1.9693x; 1.0177x over previous
//
#include <hip/hip_runtime.h>
#include <stdint.h>

#define F_IN  128
#define HID   16
#define F_OUT 128
#define NBK   256    // coarse dst buckets
#define NBLK  256    // partition blocks
#define LCAP  512    // per-bucket node capacity (>= ceil(N/NBK)+1)

__global__ void k_zero(int* __restrict__ p, int n) {
    int i = blockIdx.x * blockDim.x + threadIdx.x;
    if (i < n) p[i] = 0;
}

__device__ __forceinline__ int bucket_of(int d, int N) {
    return (int)(((long long)d * NBK) / N);
}

__device__ __forceinline__ int bucket_lo(int b, int N) {
    return (int)(((long long)b * N + NBK - 1) / NBK);
}

// ---------- pass A: coarse histogram over dst buckets (LDS-staged) ----------
__global__ void k_bhist(const int* __restrict__ dst, int* __restrict__ bh, int E, int N) {
    __shared__ int h[NBK];
    int t = threadIdx.x;
    for (int i = t; i < NBK; i += 256) h[i] = 0;
    __syncthreads();
    for (int e = blockIdx.x * 256 + t; e < E; e += gridDim.x * 256)
        atomicAdd(&h[bucket_of(dst[e], N)], 1);
    __syncthreads();
    int i = (t + blockIdx.x) & (NBK - 1);   // rotate to stagger contention
    int v = h[i];
    if (v) atomicAdd(&bh[i], v);
}

// ---------- pass B: scan bucket counts ----------
__global__ void k_bscan(const int* __restrict__ bh, int* __restrict__ bstart,
                        int* __restrict__ bcur) {
    __shared__ int s[NBK];
    int t = threadIdx.x;
    int v = bh[t];
    s[t] = v; __syncthreads();
    for (int o = 1; o < NBK; o <<= 1) {
        int x = (t >= o) ? s[t - o] : 0;
        __syncthreads();
        s[t] += x;
        __syncthreads();
    }
    int excl = s[t] - v;
    bstart[t] = excl;
    bcur[t]   = excl;
    if (t == NBK - 1) bstart[NBK] = s[t];
}

// ---------- pass C: partition with per-block range reservation ----------
// packed pair: (src << 10) | (dst - bucket_lo)   [src<2^22, local<1024]
__global__ void k_part2(const int* __restrict__ ei, int* __restrict__ bcur,
                        uint32_t* __restrict__ pairs, int E, int N) {
    __shared__ int lh[NBK], lbase[NBK], lcur[NBK], lnlo[NBK];
    int blk = blockIdx.x, t = threadIdx.x;
    int C = (E + NBLK - 1) / NBLK;
    int e0 = blk * C;
    int e1 = e0 + C; if (e1 > E) e1 = E;
    for (int i = t; i < NBK; i += 256) { lh[i] = 0; lcur[i] = 0; lnlo[i] = bucket_lo(i, N); }
    __syncthreads();
    for (int e = e0 + t; e < e1; e += 256)
        atomicAdd(&lh[bucket_of(ei[E + e], N)], 1);
    __syncthreads();
    {   // one global atomic per (block,bucket), rotated to stagger
        int i = (t + blk) & (NBK - 1);
        lbase[i] = lh[i] ? atomicAdd(&bcur[i], lh[i]) : 0;
    }
    __syncthreads();
    for (int e = e0 + t; e < e1; e += 256) {
        int s = ei[e];
        int d = ei[E + e];
        int b = bucket_of(d, N);
        int pos = lbase[b] + atomicAdd(&lcur[b], 1);
        pairs[pos] = ((uint32_t)s << 10) | (uint32_t)(d - lnlo[b]);
    }
}

// ---------- pass D: per-bucket CSR build (block = bucket, LDS-local) ----------
__global__ void k_csr(const uint32_t* __restrict__ pairs, const int* __restrict__ bstart,
                      int* __restrict__ row_start, int* __restrict__ cnt,
                      float* __restrict__ dinv, int* __restrict__ srcs, int N) {
    __shared__ int lcnt[LCAP];
    __shared__ int loff[LCAP];
    __shared__ int lcur[LCAP];
    int b = blockIdx.x, t = threadIdx.x;
    int e0 = bstart[b], e1 = bstart[b + 1];
    int nlo = bucket_lo(b, N);
    int nhi = bucket_lo(b + 1, N);
    if (nhi > N) nhi = N;
    int nn = nhi - nlo;
    lcnt[t] = 0; lcnt[t + 256] = 0;
    __syncthreads();
    for (int e = e0 + t; e < e1; e += 256)
        atomicAdd(&lcnt[pairs[e] & 1023u], 1);
    __syncthreads();
    int v0 = lcnt[t], v1 = lcnt[t + 256];
    loff[t] = v0; loff[t + 256] = v1;
    __syncthreads();
    for (int o = 1; o < LCAP; o <<= 1) {
        int a0 = (t >= o) ? loff[t - o] : 0;
        int a1 = (t + 256 >= o) ? loff[t + 256 - o] : 0;
        __syncthreads();
        loff[t] += a0; loff[t + 256] += a1;
        __syncthreads();
    }
    if (t < nn) {
        int gs = e0 + (loff[t] - v0);
        row_start[nlo + t] = gs;
        cnt[nlo + t]       = v0;
        dinv[nlo + t]      = rsqrtf((float)(v0 + 1));
        lcur[t]            = gs;
    }
    int t2 = t + 256;
    if (t2 < nn) {
        int gs = e0 + (loff[t2] - v1);
        row_start[nlo + t2] = gs;
        cnt[nlo + t2]       = v1;
        dinv[nlo + t2]      = rsqrtf((float)(v1 + 1));
        lcur[t2]            = gs;
    }
    __syncthreads();
    for (int e = e0 + t; e < e1; e += 256) {
        uint32_t p = pairs[e];
        int pos = atomicAdd(&lcur[p & 1023u], 1);
        srcs[pos] = (int)(p >> 10);
    }
}

// ---------- layer 1 transform: g1 = dinv * (x @ W1) ----------
// 64 nodes/block, 2x2 register tile per thread, padded LDS, float4 reads.
#define XP 132   // padded row stride
__global__ void __launch_bounds__(256) k_transform1(
        const float* __restrict__ x, const float* __restrict__ W1,
        const float* __restrict__ dinv, float* __restrict__ g1, int n) {
    __shared__ float sX[64 * XP];      // 33 KB
    __shared__ float sWt[HID * XP];    // 8.25 KB, [f][k]
    int t = threadIdx.x;
    int node0 = blockIdx.x * 64;
    // W1 transposed into LDS: [k][f] -> sWt[f][k]
    for (int i = t; i < F_IN * HID; i += 256) {
        int k = i >> 4, f = i & 15;
        sWt[f * XP + k] = W1[i];
    }
    // x tile: 8192 floats as float4
    const float4* x4 = (const float4*)(x + (size_t)node0 * F_IN);
    for (int j = 0; j < 8; ++j) {
        int idx4 = t + j * 256;
        int elem = idx4 * 4;
        int nl = elem >> 7, kk = elem & 127;
        float4 v = make_float4(0.f, 0.f, 0.f, 0.f);
        if (node0 + nl < n) v = x4[idx4];
        *(float4*)&sX[nl * XP + kk] = v;
    }
    __syncthreads();
    int flo = t & 7;            // f pair: flo, flo+8
    int nl  = t >> 3;           // node pair: nl, nl+32
    float a00 = 0.f, a01 = 0.f, a10 = 0.f, a11 = 0.f;
    const float* xa = &sX[nl * XP];
    const float* xb = &sX[(nl + 32) * XP];
    const float* w0 = &sWt[flo * XP];
    const float* w1 = &sWt[(flo + 8) * XP];
#pragma unroll
    for (int k = 0; k < F_IN; k += 4) {
        float4 va = *(const float4*)(xa + k);
        float4 vb = *(const float4*)(xb + k);
        float4 u0 = *(const float4*)(w0 + k);
        float4 u1 = *(const float4*)(w1 + k);
        a00 += va.x * u0.x + va.y * u0.y + va.z * u0.z + va.w * u0.w;
        a01 += va.x * u1.x + va.y * u1.y + va.z * u1.z + va.w * u1.w;
        a10 += vb.x * u0.x + vb.y * u0.y + vb.z * u0.z + vb.w * u0.w;
        a11 += vb.x * u1.x + vb.y * u1.y + vb.z * u1.z + vb.w * u1.w;
    }
    int na = node0 + nl, nb = node0 + nl + 32;
    if (na < n) {
        float di = dinv[na];
        g1[(size_t)na * HID + flo]     = di * a00;
        g1[(size_t)na * HID + flo + 8] = di * a01;
    }
    if (nb < n) {
        float di = dinv[nb];
        g1[(size_t)nb * HID + flo]     = di * a10;
        g1[(size_t)nb * HID + flo + 8] = di * a11;
    }
}

// ---------- gather-aggregate: out[i] = g[i] + sum_j g[srcs[rs+j]] ----------
template<bool EP1>
__global__ void k_gather(const float* __restrict__ g, const int* __restrict__ srcs,
                         const int* __restrict__ row_start, const int* __restrict__ cnt,
                         const float* __restrict__ dinv, const float* __restrict__ b1,
                         float* __restrict__ outb, int n) {
    int t = blockIdx.x * blockDim.x + threadIdx.x;
    int node = t >> 2;
    int p = t & 3;
    if (node >= n) return;
    int rs  = row_start[node];
    int deg = cnt[node];
    float4 acc = *(const float4*)(g + (size_t)node * HID + p * 4);
    int j = 0;
    for (; j + 8 <= deg; j += 8) {
        int s0 = srcs[rs + j + 0], s1 = srcs[rs + j + 1];
        int s2 = srcs[rs + j + 2], s3 = srcs[rs + j + 3];
        int s4 = srcs[rs + j + 4], s5 = srcs[rs + j + 5];
        int s6 = srcs[rs + j + 6], s7 = srcs[rs + j + 7];
        float4 v0 = *(const float4*)(g + (size_t)s0 * HID + p * 4);
        float4 v1 = *(const float4*)(g + (size_t)s1 * HID + p * 4);
        float4 v2 = *(const float4*)(g + (size_t)s2 * HID + p * 4);
        float4 v3 = *(const float4*)(g + (size_t)s3 * HID + p * 4);
        float4 v4 = *(const float4*)(g + (size_t)s4 * HID + p * 4);
        float4 v5 = *(const float4*)(g + (size_t)s5 * HID + p * 4);
        float4 v6 = *(const float4*)(g + (size_t)s6 * HID + p * 4);
        float4 v7 = *(const float4*)(g + (size_t)s7 * HID + p * 4);
        acc.x += ((v0.x + v1.x) + (v2.x + v3.x)) + ((v4.x + v5.x) + (v6.x + v7.x));
        acc.y += ((v0.y + v1.y) + (v2.y + v3.y)) + ((v4.y + v5.y) + (v6.y + v7.y));
        acc.z += ((v0.z + v1.z) + (v2.z + v3.z)) + ((v4.z + v5.z) + (v6.z + v7.z));
        acc.w += ((v0.w + v1.w) + (v2.w + v3.w)) + ((v4.w + v5.w) + (v6.w + v7.w));
    }
    for (; j + 2 <= deg; j += 2) {
        int s0 = srcs[rs + j], s1 = srcs[rs + j + 1];
        float4 v0 = *(const float4*)(g + (size_t)s0 * HID + p * 4);
        float4 v1 = *(const float4*)(g + (size_t)s1 * HID + p * 4);
        acc.x += v0.x + v1.x; acc.y += v0.y + v1.y;
        acc.z += v0.z + v1.z; acc.w += v0.w + v1.w;
    }
    if (j < deg) {
        int s0 = srcs[rs + j];
        float4 v0 = *(const float4*)(g + (size_t)s0 * HID + p * 4);
        acc.x += v0.x; acc.y += v0.y; acc.z += v0.z; acc.w += v0.w;
    }
    if (EP1) {
        float di = dinv[node];
        acc.x = di * fmaxf(di * acc.x + b1[p * 4 + 0], 0.0f);
        acc.y = di * fmaxf(di * acc.y + b1[p * 4 + 1], 0.0f);
        acc.z = di * fmaxf(di * acc.z + b1[p * 4 + 2], 0.0f);
        acc.w = di * fmaxf(di * acc.w + b1[p * 4 + 3], 0.0f);
    }
    *(float4*)(outb + (size_t)node * HID + p * 4) = acc;
}

// ---------- layer 2 transform: out = relu(dinv*(agg @ W2) + b2) ----------
// 32 nodes/block, W2 column in registers, agg loads are wave-uniform (L1 bcast).
__global__ void __launch_bounds__(256) k_transform2(
        const float* __restrict__ agg, const float* __restrict__ W2,
        const float* __restrict__ b2, const float* __restrict__ dinv,
        float* __restrict__ out, int n) {
    int t = threadIdx.x;
    int d = t & 127;
    int h = t >> 7;
    int node0 = blockIdx.x * 32;
    float wcol[HID];
#pragma unroll
    for (int f = 0; f < HID; ++f) wcol[f] = W2[f * F_OUT + d];
    float bd = b2[d];
#pragma unroll 4
    for (int i = 0; i < 16; ++i) {
        int node = node0 + h + 2 * i;
        if (node >= n) continue;
        const float4* av = (const float4*)(agg + (size_t)node * HID);
        float4 v0 = av[0], v1 = av[1], v2 = av[2], v3 = av[3];
        float s = v0.x * wcol[0]  + v0.y * wcol[1]  + v0.z * wcol[2]  + v0.w * wcol[3]
                + v1.x * wcol[4]  + v1.y * wcol[5]  + v1.z * wcol[6]  + v1.w * wcol[7]
                + v2.x * wcol[8]  + v2.y * wcol[9]  + v2.z * wcol[10] + v2.w * wcol[11]
                + v3.x * wcol[12] + v3.y * wcol[13] + v3.z * wcol[14] + v3.w * wcol[15];
        out[(size_t)node * F_OUT + d] = fmaxf(dinv[node] * s + bd, 0.0f);
    }
}

extern "C" void kernel_launch(void* const* d_in, const int* in_sizes, int n_in,
                              void* d_out, int out_size, void* d_ws, size_t ws_size,
                              hipStream_t stream) {
    const float* x  = (const float*)d_in[0];
    const int*   ei = (const int*)d_in[1];
    const float* W1 = (const float*)d_in[2];
    const float* b1 = (const float*)d_in[3];
    const float* W2 = (const float*)d_in[4];
    const float* b2 = (const float*)d_in[5];
    float* out = (float*)d_out;

    const int N = in_sizes[0] / F_IN;
    const int E = in_sizes[1] / 2;

    // workspace layout
    float* dinv      = (float*)d_ws;                   // N
    int*   cnt       = (int*)(dinv + N);               // N
    int*   row_start = cnt + N;                        // N
    int*   bh        = row_start + N;                  // NBK
    int*   bstart    = bh + NBK;                       // NBK+1
    int*   bcur      = bstart + NBK + 1;               // NBK
    int*   srcs      = bcur + NBK;                     // E
    uintptr_t xb = (uintptr_t)(srcs + E);
    xb = (xb + 15) & ~(uintptr_t)15;
    uint32_t* pairs = (uint32_t*)xb;                   // E uint32 (build phase)
    float* bufA  = (float*)xb;                         // N*HID (reuses pairs region)
    float* bufB  = bufA + (size_t)N * HID;             // N*HID

    k_zero <<<1, NBK, 0, stream>>>(bh, NBK);
    k_bhist<<<256, 256, 0, stream>>>(ei + E, bh, E, N);
    k_bscan<<<1, NBK, 0, stream>>>(bh, bstart, bcur);
    k_part2<<<NBLK, 256, 0, stream>>>(ei, bcur, pairs, E, N);
    k_csr  <<<NBK, 256, 0, stream>>>(pairs, bstart, row_start, cnt, dinv, srcs, N);

    k_transform1<<<(N + 63) / 64, 256, 0, stream>>>(x, W1, dinv, bufA, N);
    k_gather<true> <<<((size_t)N * 4 + 255) / 256, 256, 0, stream>>>(
        bufA, srcs, row_start, cnt, dinv, b1, bufB, N);
    k_gather<false><<<((size_t)N * 4 + 255) / 256, 256, 0, stream>>>(
        bufB, srcs, row_start, cnt, dinv, b1, bufA, N);
    k_transform2<<<(N + 31) / 32, 256, 0, stream>>>(bufA, W2, b2, dinv, out, N);
}

// Round 6
// 268.199 us; speedup vs baseline: 2.1920x; 1.1131x over previous
//
#include <hip/hip_runtime.h>
#include <stdint.h>

#define F_IN  128
#define HID   16
#define F_OUT 128
#define NBK   256    // coarse dst buckets
#define NBLK  256    // partition blocks
#define LCAP  512    // per-bucket node capacity (>= ceil(N/NBK)+1)

__global__ void k_zero(int* __restrict__ p, int n) {
    int i = blockIdx.x * blockDim.x + threadIdx.x;
    if (i < n) p[i] = 0;
}

__device__ __forceinline__ int bucket_of(int d, int N) {
    return (int)(((long long)d * NBK) / N);
}

__device__ __forceinline__ int bucket_lo(int b, int N) {
    return (int)(((long long)b * N + NBK - 1) / NBK);
}

// ---------- pass A: coarse histogram over dst buckets (LDS-staged) ----------
__global__ void k_bhist(const int* __restrict__ dst, int* __restrict__ bh, int E, int N) {
    __shared__ int h[NBK];
    int t = threadIdx.x;
    for (int i = t; i < NBK; i += 256) h[i] = 0;
    __syncthreads();
    for (int e = blockIdx.x * 256 + t; e < E; e += gridDim.x * 256)
        atomicAdd(&h[bucket_of(dst[e], N)], 1);
    __syncthreads();
    int i = (t + blockIdx.x) & (NBK - 1);   // rotate to stagger contention
    int v = h[i];
    if (v) atomicAdd(&bh[i], v);
}

// ---------- pass B: scan bucket counts ----------
__global__ void k_bscan(const int* __restrict__ bh, int* __restrict__ bstart,
                        int* __restrict__ bcur) {
    __shared__ int s[NBK];
    int t = threadIdx.x;
    int v = bh[t];
    s[t] = v; __syncthreads();
    for (int o = 1; o < NBK; o <<= 1) {
        int x = (t >= o) ? s[t - o] : 0;
        __syncthreads();
        s[t] += x;
        __syncthreads();
    }
    int excl = s[t] - v;
    bstart[t] = excl;
    bcur[t]   = excl;
    if (t == NBK - 1) bstart[NBK] = s[t];
}

// ---------- pass C: partition with per-block range reservation ----------
// packed pair: (src << 10) | (dst - bucket_lo)   [src<2^22, local<1024]
__global__ void k_part2(const int* __restrict__ ei, int* __restrict__ bcur,
                        uint32_t* __restrict__ pairs, int E, int N) {
    __shared__ int lh[NBK], lbase[NBK], lcur[NBK], lnlo[NBK];
    int blk = blockIdx.x, t = threadIdx.x;
    int C = (E + NBLK - 1) / NBLK;
    int e0 = blk * C;
    int e1 = e0 + C; if (e1 > E) e1 = E;
    for (int i = t; i < NBK; i += 256) { lh[i] = 0; lcur[i] = 0; lnlo[i] = bucket_lo(i, N); }
    __syncthreads();
    for (int e = e0 + t; e < e1; e += 256)
        atomicAdd(&lh[bucket_of(ei[E + e], N)], 1);
    __syncthreads();
    {   // one global atomic per (block,bucket), rotated to stagger
        int i = (t + blk) & (NBK - 1);
        lbase[i] = lh[i] ? atomicAdd(&bcur[i], lh[i]) : 0;
    }
    __syncthreads();
    for (int e = e0 + t; e < e1; e += 256) {
        int s = ei[e];
        int d = ei[E + e];
        int b = bucket_of(d, N);
        int pos = lbase[b] + atomicAdd(&lcur[b], 1);
        pairs[pos] = ((uint32_t)s << 10) | (uint32_t)(d - lnlo[b]);
    }
}

// ---------- pass D: per-bucket CSR build (block = bucket, LDS-local) ----------
__global__ void k_csr(const uint32_t* __restrict__ pairs, const int* __restrict__ bstart,
                      int* __restrict__ row_start, int* __restrict__ cnt,
                      float* __restrict__ dinv, int* __restrict__ srcs, int N) {
    __shared__ int lcnt[LCAP];
    __shared__ int loff[LCAP];
    __shared__ int lcur[LCAP];
    int b = blockIdx.x, t = threadIdx.x;
    int e0 = bstart[b], e1 = bstart[b + 1];
    int nlo = bucket_lo(b, N);
    int nhi = bucket_lo(b + 1, N);
    if (nhi > N) nhi = N;
    int nn = nhi - nlo;
    lcnt[t] = 0; lcnt[t + 256] = 0;
    __syncthreads();
    for (int e = e0 + t; e < e1; e += 256)
        atomicAdd(&lcnt[pairs[e] & 1023u], 1);
    __syncthreads();
    int v0 = lcnt[t], v1 = lcnt[t + 256];
    loff[t] = v0; loff[t + 256] = v1;
    __syncthreads();
    for (int o = 1; o < LCAP; o <<= 1) {
        int a0 = (t >= o) ? loff[t - o] : 0;
        int a1 = (t + 256 >= o) ? loff[t + 256 - o] : 0;
        __syncthreads();
        loff[t] += a0; loff[t + 256] += a1;
        __syncthreads();
    }
    if (t < nn) {
        int gs = e0 + (loff[t] - v0);
        row_start[nlo + t] = gs;
        cnt[nlo + t]       = v0;
        dinv[nlo + t]      = rsqrtf((float)(v0 + 1));
        lcur[t]            = gs;
    }
    int t2 = t + 256;
    if (t2 < nn) {
        int gs = e0 + (loff[t2] - v1);
        row_start[nlo + t2] = gs;
        cnt[nlo + t2]       = v1;
        dinv[nlo + t2]      = rsqrtf((float)(v1 + 1));
        lcur[t2]            = gs;
    }
    __syncthreads();
    for (int e = e0 + t; e < e1; e += 256) {
        uint32_t p = pairs[e];
        int pos = atomicAdd(&lcur[p & 1023u], 1);
        srcs[pos] = (int)(p >> 10);
    }
}

// ---------- layer 1 transform: g1 = dinv * (x @ W1) ----------
// 32 nodes/block, 2 outputs/thread (f, f+8), float4 LDS reads, low VGPR.
#define XP1 132   // padded row stride (132 % 32 == 4 -> conflict-free phases)
__global__ void __launch_bounds__(256) k_transform1(
        const float* __restrict__ x, const float* __restrict__ W1,
        const float* __restrict__ dinv, float* __restrict__ g1, int n) {
    __shared__ float sX[32 * XP1];     // 16.9 KB
    __shared__ float sWt[HID * XP1];   // 8.45 KB, [f][k]
    int t = threadIdx.x;
    int node0 = blockIdx.x * 32;
    // W1 transposed into LDS: [k][f] -> sWt[f][k]
    for (int i = t; i < F_IN * HID; i += 256) {
        int k = i >> 4, f = i & 15;
        sWt[f * XP1 + k] = W1[i];
    }
    // x tile: 32 rows x 128 = 1024 float4, 4 per thread, coalesced
    const float4* x4 = (const float4*)(x + (size_t)node0 * F_IN);
    int nrem = n - node0;
#pragma unroll
    for (int j = 0; j < 4; ++j) {
        int idx4 = t + j * 256;
        int nl = idx4 >> 5;            // row (32 float4 per row)
        int kk = (idx4 & 31) * 4;
        float4 v = make_float4(0.f, 0.f, 0.f, 0.f);
        if (nl < nrem) v = x4[idx4];
        *(float4*)&sX[nl * XP1 + kk] = v;
    }
    __syncthreads();
    int f  = t & 7;        // outputs f and f+8
    int nl = t >> 3;       // local node 0..31
    float a0 = 0.f, a1 = 0.f;
    const float* xr  = &sX[nl * XP1];
    const float* wr0 = &sWt[f * XP1];
    const float* wr1 = &sWt[(f + 8) * XP1];
#pragma unroll 4
    for (int k = 0; k < F_IN; k += 4) {
        float4 xv = *(const float4*)(xr + k);
        float4 w0 = *(const float4*)(wr0 + k);
        float4 w1 = *(const float4*)(wr1 + k);
        a0 += xv.x * w0.x + xv.y * w0.y + xv.z * w0.z + xv.w * w0.w;
        a1 += xv.x * w1.x + xv.y * w1.y + xv.z * w1.z + xv.w * w1.w;
    }
    int node = node0 + nl;
    if (node < n) {
        float di = dinv[node];
        g1[(size_t)node * HID + f]     = di * a0;
        g1[(size_t)node * HID + f + 8] = di * a1;
    }
}

// ---------- gather-aggregate: out[i] = g[i] + sum_j g[srcs[rs+j]] ----------
template<bool EP1>
__global__ void k_gather(const float* __restrict__ g, const int* __restrict__ srcs,
                         const int* __restrict__ row_start, const int* __restrict__ cnt,
                         const float* __restrict__ dinv, const float* __restrict__ b1,
                         float* __restrict__ outb, int n) {
    int t = blockIdx.x * blockDim.x + threadIdx.x;
    int node = t >> 2;
    int p = t & 3;
    if (node >= n) return;
    int rs  = row_start[node];
    int deg = cnt[node];
    float4 acc = *(const float4*)(g + (size_t)node * HID + p * 4);
    int j = 0;
    for (; j + 8 <= deg; j += 8) {
        int s0 = srcs[rs + j + 0], s1 = srcs[rs + j + 1];
        int s2 = srcs[rs + j + 2], s3 = srcs[rs + j + 3];
        int s4 = srcs[rs + j + 4], s5 = srcs[rs + j + 5];
        int s6 = srcs[rs + j + 6], s7 = srcs[rs + j + 7];
        float4 v0 = *(const float4*)(g + (size_t)s0 * HID + p * 4);
        float4 v1 = *(const float4*)(g + (size_t)s1 * HID + p * 4);
        float4 v2 = *(const float4*)(g + (size_t)s2 * HID + p * 4);
        float4 v3 = *(const float4*)(g + (size_t)s3 * HID + p * 4);
        float4 v4 = *(const float4*)(g + (size_t)s4 * HID + p * 4);
        float4 v5 = *(const float4*)(g + (size_t)s5 * HID + p * 4);
        float4 v6 = *(const float4*)(g + (size_t)s6 * HID + p * 4);
        float4 v7 = *(const float4*)(g + (size_t)s7 * HID + p * 4);
        acc.x += ((v0.x + v1.x) + (v2.x + v3.x)) + ((v4.x + v5.x) + (v6.x + v7.x));
        acc.y += ((v0.y + v1.y) + (v2.y + v3.y)) + ((v4.y + v5.y) + (v6.y + v7.y));
        acc.z += ((v0.z + v1.z) + (v2.z + v3.z)) + ((v4.z + v5.z) + (v6.z + v7.z));
        acc.w += ((v0.w + v1.w) + (v2.w + v3.w)) + ((v4.w + v5.w) + (v6.w + v7.w));
    }
    for (; j + 2 <= deg; j += 2) {
        int s0 = srcs[rs + j], s1 = srcs[rs + j + 1];
        float4 v0 = *(const float4*)(g + (size_t)s0 * HID + p * 4);
        float4 v1 = *(const float4*)(g + (size_t)s1 * HID + p * 4);
        acc.x += v0.x + v1.x; acc.y += v0.y + v1.y;
        acc.z += v0.z + v1.z; acc.w += v0.w + v1.w;
    }
    if (j < deg) {
        int s0 = srcs[rs + j];
        float4 v0 = *(const float4*)(g + (size_t)s0 * HID + p * 4);
        acc.x += v0.x; acc.y += v0.y; acc.z += v0.z; acc.w += v0.w;
    }
    if (EP1) {
        float di = dinv[node];
        acc.x = di * fmaxf(di * acc.x + b1[p * 4 + 0], 0.0f);
        acc.y = di * fmaxf(di * acc.y + b1[p * 4 + 1], 0.0f);
        acc.z = di * fmaxf(di * acc.z + b1[p * 4 + 2], 0.0f);
        acc.w = di * fmaxf(di * acc.w + b1[p * 4 + 3], 0.0f);
    }
    *(float4*)(outb + (size_t)node * HID + p * 4) = acc;
}

// ---------- layer 2 transform: out = relu(dinv*(agg @ W2) + b2) ----------
// 32 nodes/block, W2 column in registers, agg loads are wave-uniform (L1 bcast).
__global__ void __launch_bounds__(256) k_transform2(
        const float* __restrict__ agg, const float* __restrict__ W2,
        const float* __restrict__ b2, const float* __restrict__ dinv,
        float* __restrict__ out, int n) {
    int t = threadIdx.x;
    int d = t & 127;
    int h = t >> 7;
    int node0 = blockIdx.x * 32;
    float wcol[HID];
#pragma unroll
    for (int f = 0; f < HID; ++f) wcol[f] = W2[f * F_OUT + d];
    float bd = b2[d];
#pragma unroll 4
    for (int i = 0; i < 16; ++i) {
        int node = node0 + h + 2 * i;
        if (node >= n) continue;
        const float4* av = (const float4*)(agg + (size_t)node * HID);
        float4 v0 = av[0], v1 = av[1], v2 = av[2], v3 = av[3];
        float s = v0.x * wcol[0]  + v0.y * wcol[1]  + v0.z * wcol[2]  + v0.w * wcol[3]
                + v1.x * wcol[4]  + v1.y * wcol[5]  + v1.z * wcol[6]  + v1.w * wcol[7]
                + v2.x * wcol[8]  + v2.y * wcol[9]  + v2.z * wcol[10] + v2.w * wcol[11]
                + v3.x * wcol[12] + v3.y * wcol[13] + v3.z * wcol[14] + v3.w * wcol[15];
        out[(size_t)node * F_OUT + d] = fmaxf(dinv[node] * s + bd, 0.0f);
    }
}

extern "C" void kernel_launch(void* const* d_in, const int* in_sizes, int n_in,
                              void* d_out, int out_size, void* d_ws, size_t ws_size,
                              hipStream_t stream) {
    const float* x  = (const float*)d_in[0];
    const int*   ei = (const int*)d_in[1];
    const float* W1 = (const float*)d_in[2];
    const float* b1 = (const float*)d_in[3];
    const float* W2 = (const float*)d_in[4];
    const float* b2 = (const float*)d_in[5];
    float* out = (float*)d_out;

    const int N = in_sizes[0] / F_IN;
    const int E = in_sizes[1] / 2;

    // workspace layout
    float* dinv      = (float*)d_ws;                   // N
    int*   cnt       = (int*)(dinv + N);               // N
    int*   row_start = cnt + N;                        // N
    int*   bh        = row_start + N;                  // NBK
    int*   bstart    = bh + NBK;                       // NBK+1
    int*   bcur      = bstart + NBK + 1;               // NBK
    int*   srcs      = bcur + NBK;                     // E
    uintptr_t xb = (uintptr_t)(srcs + E);
    xb = (xb + 15) & ~(uintptr_t)15;
    uint32_t* pairs = (uint32_t*)xb;                   // E uint32 (build phase)
    float* bufA  = (float*)xb;                         // N*HID (reuses pairs region)
    float* bufB  = bufA + (size_t)N * HID;             // N*HID

    k_zero <<<1, NBK, 0, stream>>>(bh, NBK);
    k_bhist<<<256, 256, 0, stream>>>(ei + E, bh, E, N);
    k_bscan<<<1, NBK, 0, stream>>>(bh, bstart, bcur);
    k_part2<<<NBLK, 256, 0, stream>>>(ei, bcur, pairs, E, N);
    k_csr  <<<NBK, 256, 0, stream>>>(pairs, bstart, row_start, cnt, dinv, srcs, N);

    k_transform1<<<(N + 31) / 32, 256, 0, stream>>>(x, W1, dinv, bufA, N);
    k_gather<true> <<<((size_t)N * 4 + 255) / 256, 256, 0, stream>>>(
        bufA, srcs, row_start, cnt, dinv, b1, bufB, N);
    k_gather<false><<<((size_t)N * 4 + 255) / 256, 256, 0, stream>>>(
        bufB, srcs, row_start, cnt, dinv, b1, bufA, N);
    k_transform2<<<(N + 31) / 32, 256, 0, stream>>>(bufA, W2, b2, dinv, out, N);
}